// Round 11
// baseline (143.625 us; speedup 1.0000x reference)
//
#include <hip/hip_runtime.h>
#include <stdint.h>

#define BB 8
#define C  64
#define H  256
#define W  256
#define HW (H*W)
#define EPSV 1e-6f

typedef unsigned long long u64;
typedef float __attribute__((ext_vector_type(4))) f32x4;
typedef int __attribute__((ext_vector_type(4)))  v4i;
typedef int __attribute__((ext_vector_type(16))) v16i;

// ---------------- K1a: per-(b,c) stats, pure streaming (R10 identical) ------
__global__ __launch_bounds__(256) void k_stats(const float* __restrict__ x,
                                               const float* __restrict__ bmove,
                                               float* __restrict__ sums /* [3][512] */) {
  int bc = blockIdx.x;
  float bm = bmove[bc & 63];
  const f32x4* p = (const f32x4*)(x + (size_t)bc * HW);
  int t = threadIdx.x;
  float s = 0.f, s2 = 0.f, sa = 0.f;
  #pragma unroll 8
  for (int k = 0; k < 64; ++k) {
    f32x4 v = p[(k << 8) | t];
    float a0 = v.x + bm, a1 = v.y + bm, a2 = v.z + bm, a3 = v.w + bm;
    s  += a0 + a1 + a2 + a3;
    s2 += a0*a0 + a1*a1 + a2*a2 + a3*a3;
    sa += fabsf(a0) + fabsf(a1) + fabsf(a2) + fabsf(a3);
  }
  #pragma unroll
  for (int off = 32; off > 0; off >>= 1) {
    s  += __shfl_down(s,  off, 64);
    s2 += __shfl_down(s2, off, 64);
    sa += __shfl_down(sa, off, 64);
  }
  __shared__ float red[4][3];
  int wid = t >> 6;
  if ((t & 63) == 0) { red[wid][0] = s; red[wid][1] = s2; red[wid][2] = sa; }
  __syncthreads();
  if (t == 0) {
    float S  = red[0][0] + red[1][0] + red[2][0] + red[3][0];
    float S2 = red[0][1] + red[1][1] + red[2][1] + red[3][1];
    float SA = red[0][2] + red[1][2] + red[2][2] + red[3][2];
    sums[bc] = S; sums[512 + bc] = S2; sums[1024 + bc] = SA;
  }
}

// ---------------- K1b: LDS-transpose + ballot sign-pack (R10 identical) -----
__global__ __launch_bounds__(256) void k_pack(const float* __restrict__ x,
                                              const float* __restrict__ bmove,
                                              u64* __restrict__ packed) {
  int blk = blockIdx.x;
  int b   = blk >> 7;
  int rg  = blk & 127;
  int h0  = rg << 1;
  int tid = threadIdx.x;
  int wid = tid >> 6, lane = tid & 63;
  __shared__ f32x4 lds4[64 * 33];

  float bm = bmove[lane];               // lane = channel in consume phase
  int p4l = tid & 31;
  int cg  = tid >> 5;
  const size_t bbase = (size_t)b * C * HW;

  for (int tile = 0; tile < 4; ++tile) {
    int h  = h0 + (tile >> 1);
    int wb = (tile & 1) << 7;
    __syncthreads();
    #pragma unroll
    for (int cc = 0; cc < 8; ++cc) {
      int c = cg + (cc << 3);
      lds4[c * 33 + p4l] =
          *((const f32x4*)(x + bbase + (size_t)c * HW + h * W + wb) + p4l);
    }
    __syncthreads();
    u64* pdst = packed + ((size_t)(b * H + h)) * W + wb;
    #pragma unroll
    for (int k = 0; k < 8; ++k) {
      int p4i = (wid << 3) + k;
      f32x4 v = lds4[lane * 33 + p4i];
      u64 q0 = __ballot(v.x + bm > 0.f);
      u64 q1 = __ballot(v.y + bm > 0.f);
      u64 q2 = __ballot(v.z + bm > 0.f);
      u64 q3 = __ballot(v.w + bm > 0.f);
      u64 qa = (lane & 1) ? q1 : q0;
      u64 qb = (lane & 1) ? q3 : q2;
      u64 qq = (lane & 2) ? qb : qa;
      if (lane < 4) pdst[(p4i << 2) + lane] = qq;
    }
  }
}

// -------- K2: gate + sumw table + i8 A-fragment table -----------------------
__global__ __launch_bounds__(512) void k_gate(const float* __restrict__ sums,
                                              const float* __restrict__ w_conv,
                                              const float* __restrict__ w1d,
                                              float* __restrict__ alpha,
                                              float* __restrict__ sumw_g,
                                              char*  __restrict__ atab) {
  __shared__ float stA[512], stM[512], stS[512];  // [b*64 + c]
  __shared__ float swv[64];
  __shared__ float stap[64][9];                   // per-(o,tap) sign-sum
  int tid = threadIdx.x;

  // A-table: [mt(2)][ks(18)][lane(64)] x 16 bytes; byte j = sign(w[o][c0+j][tap])
  for (int e = tid; e < 2304; e += 512) {
    int mt = e / 1152; int rem = e - mt * 1152;
    int ks = rem >> 6;  int l = rem & 63;
    int o  = mt * 32 + (l & 31);
    int st = ks & 1;    int tap = ks >> 1;
    int c0 = st * 32 + (l >> 5) * 16;
    unsigned q[4];
    #pragma unroll
    for (int qi = 0; qi < 4; ++qi) {
      unsigned v = 0;
      #pragma unroll
      for (int j = 0; j < 4; ++j) {
        int c = c0 + qi * 4 + j;
        float wv = w_conv[o * 576 + c * 9 + tap];
        unsigned by = (wv > 0.f) ? 0x01u : 0xFFu;   // i8 +1 / -1
        v |= by << (8 * j);
      }
      q[qi] = v;
    }
    v4i qv; qv.x = (int)q[0]; qv.y = (int)q[1]; qv.z = (int)q[2]; qv.w = (int)q[3];
    *(v4i*)(atab + (size_t)e * 16) = qv;
  }

  {
    float s = sums[tid], s2 = sums[512 + tid], sa = sums[1024 + tid];
    const float invN = 1.f / (float)HW;
    float mean = s * invN;
    float var  = (s2 - s * s * invN) * (1.f / (float)(HW - 1)) + EPSV;
    stA[tid] = sa * invN;
    stM[tid] = mean;
    stS[tid] = sqrtf(var);
  }
  {
    int o = tid >> 3, g = tid & 7;                 // 8 lanes per out-channel
    const float* wo = w_conv + o * 576 + g * 72;   // 8 in-channels x 9 taps
    float s = 0.f;
    u64 wb[9] = {0,0,0,0,0,0,0,0,0};
    #pragma unroll
    for (int i = 0; i < 8; i++) {
      #pragma unroll
      for (int tp = 0; tp < 9; tp++) {
        float v = wo[i * 9 + tp];
        s += fabsf(v);
        if (v > 0.f) wb[tp] |= (1ull << (g * 8 + i));
      }
    }
    #pragma unroll
    for (int off = 4; off > 0; off >>= 1) {
      s += __shfl_down(s, off, 8);
      #pragma unroll
      for (int tp = 0; tp < 9; tp++)
        wb[tp] |= __shfl_down(wb[tp], off, 8);
    }
    if (g == 0) {
      swv[o] = s * (1.f / 576.f);
      #pragma unroll
      for (int tp = 0; tp < 9; tp++)
        stap[o][tp] = (float)(2 * (int)__popcll(wb[tp]) - 64);
    }
  }
  __syncthreads();
  // sumw[vc][hc][o]: vc=0 -> h==0 (dy=-1 missing), vc=2 -> h==255; same for hc/w.
  for (int i = tid; i < 576; i += 512) {
    int cse = i >> 6, o = i & 63;
    int vc = cse / 3, hc = cse - vc * 3;
    int ky0 = (vc == 0) ? 1 : 0, ky1 = (vc == 2) ? 1 : 2;
    int kx0 = (hc == 0) ? 1 : 0, kx1 = (hc == 2) ? 1 : 2;
    float sw = 0.f;
    for (int ky = ky0; ky <= ky1; ++ky)
      for (int kx = kx0; kx <= kx1; ++kx)
        sw += stap[o][ky * 3 + kx];
    sumw_g[cse * 64 + o] = sw;
  }
  int b = tid >> 6, c = tid & 63;
  float y = 0.f;
  #pragma unroll
  for (int k = 0; k < 3; k++) {
    int cc = c + k - 1;
    if (cc >= 0 && cc < 64) {
      int j = b * 64 + cc;
      y += stA[j] * w1d[0 * 3 + k] + stM[j] * w1d[1 * 3 + k] + stS[j] * w1d[2 * 3 + k];
    }
  }
  float gate = 1.f / (1.f + expf(-y));
  alpha[tid] = gate * swv[c];   // folds scale_w[o] * gate[b][o]
}

// -------- K3: i8 MFMA conv: D[o=64][px=32] per wave, K=576 ------------------
// 4096 blocks: b(3) h(8) wq(1); 4 waves -> w0 = wq*128 + wv*32.
__global__ __launch_bounds__(256) void k_convmm(const u64* __restrict__ packed,
                                                const char* __restrict__ atab,
                                                const float* __restrict__ sumw_g,
                                                const float* __restrict__ alpha,
                                                const float* __restrict__ x,
                                                const float* __restrict__ pr_b0,
                                                const float* __restrict__ prelu_a,
                                                const float* __restrict__ pr_b1,
                                                float* __restrict__ out) {
  int blk = blockIdx.x;
  int b = blk >> 9, h = (blk >> 1) & 255, wq = blk & 1;
  int tid = threadIdx.x, wv = tid >> 6, lane = tid & 63;
  int w0 = wq * 128 + wv * 32;
  int px = w0 + (lane & 31);
  int half = lane >> 5;

  __shared__ v4i  s_at[2304];           // A-fragment table (36 KB)
  __shared__ float s_sumw[576];
  __shared__ float s_al[64], s_b0[64], s_pa[64], s_b1[64];
  for (int i = tid; i < 2304; i += 256) s_at[i] = ((const v4i*)atab)[i];
  for (int i = tid; i < 576; i += 256) s_sumw[i] = sumw_g[i];
  if (tid < 64) {
    s_al[tid] = alpha[b * 64 + tid];
    s_b0[tid] = pr_b0[tid]; s_pa[tid] = prelu_a[tid]; s_b1[tid] = pr_b1[tid];
  }
  __syncthreads();

  v16i acc0 = {0,0,0,0,0,0,0,0,0,0,0,0,0,0,0,0};
  v16i acc1 = {0,0,0,0,0,0,0,0,0,0,0,0,0,0,0,0};
  const u64* pb = packed + (size_t)b * HW;
  const unsigned MAGIC = 0x00204081u;

  #pragma unroll
  for (int dy = -1; dy <= 1; ++dy) {
    int hh = h + dy;
    if (hh < 0 || hh > H - 1) continue;           // wave-uniform
    const u64* rp = pb + hh * W;
    u64 m[3];
    #pragma unroll
    for (int dx = 0; dx < 3; ++dx) {
      int wn = px + dx - 1;
      int wc = wn < 0 ? 0 : (wn > W - 1 ? W - 1 : wn);
      u64 mm = rp[wc];
      m[dx] = (wn == wc) ? mm : 0ull;             // zero mask => zero bytes => pad
    }
    #pragma unroll
    for (int dx = 0; dx < 3; ++dx) {
      int tap = (dy + 1) * 3 + dx;
      #pragma unroll
      for (int st = 0; st < 2; ++st) {
        int c0 = st * 32 + half * 16;
        unsigned n16 = (unsigned)(m[dx] >> c0) & 0xFFFFu;
        v4i bf;
        bf.x = (int)(((n16        & 0xFu) * MAGIC) & 0x01010101u);
        bf.y = (int)((((n16 >> 4) & 0xFu) * MAGIC) & 0x01010101u);
        bf.z = (int)((((n16 >> 8) & 0xFu) * MAGIC) & 0x01010101u);
        bf.w = (int)((((n16 >>12) & 0xFu) * MAGIC) & 0x01010101u);
        int ks = tap * 2 + st;
        v4i a0 = s_at[ks * 64 + lane];
        v4i a1 = s_at[(18 + ks) * 64 + lane];
        acc0 = __builtin_amdgcn_mfma_i32_32x32x32_i8(a0, bf, acc0, 0, 0, 0);
        acc1 = __builtin_amdgcn_mfma_i32_32x32x32_i8(a1, bf, acc1, 0, 0, 0);
      }
    }
  }

  int vc = (h == 0) ? 0 : ((h == H - 1) ? 2 : 1);
  int hc = (px == 0) ? 0 : ((px == W - 1) ? 2 : 1);
  const float* swrow = s_sumw + (vc * 3 + hc) * 64;
  int oadd = half * 4;
  size_t pxoff = (size_t)b * C * HW + (size_t)h * W + px;

  #pragma unroll
  for (int mt = 0; mt < 2; ++mt) {
    #pragma unroll
    for (int r = 0; r < 16; ++r) {
      int o = mt * 32 + (r & 3) + 8 * (r >> 2) + oadd;
      int a = mt ? acc1[r] : acc0[r];
      float dot = 2.0f * (float)a - swrow[o];
      float v = dot * s_al[o] + s_b0[o];
      v = (v > 0.f) ? v : s_pa[o] * v;
      v += s_b1[o] + x[pxoff + (size_t)o * HW];
      __builtin_nontemporal_store(v, out + pxoff + (size_t)o * HW);
    }
  }
}

extern "C" void kernel_launch(void* const* d_in, const int* in_sizes, int n_in,
                              void* d_out, int out_size, void* d_ws, size_t ws_size,
                              hipStream_t stream) {
  const float* x       = (const float*)d_in[0];
  const float* b_move  = (const float*)d_in[1];
  const float* w_conv  = (const float*)d_in[2];
  const float* w1d     = (const float*)d_in[3];
  const float* pr_b0   = (const float*)d_in[4];
  const float* prelu_a = (const float*)d_in[5];
  const float* pr_b1   = (const float*)d_in[6];
  float* out = (float*)d_out;

  char* ws = (char*)d_ws;
  u64*   packed = (u64*)ws;                          // 4 MiB
  float* sums   = (float*)(ws + 4194304);            // 6144 B
  float* alpha  = (float*)(ws + 4194304 + 8192);     // 2048 B
  float* sumw   = (float*)(ws + 4194304 + 24576);    // 2304 B
  char*  atab   =         (ws + 4194304 + 32768);    // 36864 B

  k_stats<<<512, 256, 0, stream>>>(x, b_move, sums);
  k_pack<<<1024, 256, 0, stream>>>(x, b_move, packed);
  k_gate<<<1, 512, 0, stream>>>(sums, w_conv, w1d, alpha, sumw, atab);
  k_convmm<<<4096, 256, 0, stream>>>(packed, atab, sumw, alpha, x,
                                     pr_b0, prelu_a, pr_b1, out);
}

// Round 12
// 107.001 us; speedup vs baseline: 1.3423x; 1.3423x over previous
//
#include <hip/hip_runtime.h>
#include <stdint.h>

#define BB 8
#define C  64
#define H  256
#define W  256
#define HW (H*W)
#define EPSV 1e-6f

typedef unsigned long long u64;
typedef float __attribute__((ext_vector_type(4))) f32x4;

// ---------------- K1a: per-(b,c) stats, pure streaming (R10 identical) ------
__global__ __launch_bounds__(256) void k_stats(const float* __restrict__ x,
                                               const float* __restrict__ bmove,
                                               float* __restrict__ sums /* [3][512] */) {
  int bc = blockIdx.x;
  float bm = bmove[bc & 63];
  const f32x4* p = (const f32x4*)(x + (size_t)bc * HW);
  int t = threadIdx.x;
  float s = 0.f, s2 = 0.f, sa = 0.f;
  #pragma unroll 8
  for (int k = 0; k < 64; ++k) {
    f32x4 v = p[(k << 8) | t];
    float a0 = v.x + bm, a1 = v.y + bm, a2 = v.z + bm, a3 = v.w + bm;
    s  += a0 + a1 + a2 + a3;
    s2 += a0*a0 + a1*a1 + a2*a2 + a3*a3;
    sa += fabsf(a0) + fabsf(a1) + fabsf(a2) + fabsf(a3);
  }
  #pragma unroll
  for (int off = 32; off > 0; off >>= 1) {
    s  += __shfl_down(s,  off, 64);
    s2 += __shfl_down(s2, off, 64);
    sa += __shfl_down(sa, off, 64);
  }
  __shared__ float red[4][3];
  int wid = t >> 6;
  if ((t & 63) == 0) { red[wid][0] = s; red[wid][1] = s2; red[wid][2] = sa; }
  __syncthreads();
  if (t == 0) {
    float S  = red[0][0] + red[1][0] + red[2][0] + red[3][0];
    float S2 = red[0][1] + red[1][1] + red[2][1] + red[3][1];
    float SA = red[0][2] + red[1][2] + red[2][2] + red[3][2];
    sums[bc] = S; sums[512 + bc] = S2; sums[1024 + bc] = SA;
  }
}

// ---------------- K1b: LDS-transpose + ballot sign-pack (R10 identical) -----
__global__ __launch_bounds__(256) void k_pack(const float* __restrict__ x,
                                              const float* __restrict__ bmove,
                                              u64* __restrict__ packed) {
  int blk = blockIdx.x;
  int b   = blk >> 7;
  int rg  = blk & 127;
  int h0  = rg << 1;
  int tid = threadIdx.x;
  int wid = tid >> 6, lane = tid & 63;
  __shared__ f32x4 lds4[64 * 33];

  float bm = bmove[lane];               // lane = channel in consume phase
  int p4l = tid & 31;
  int cg  = tid >> 5;
  const size_t bbase = (size_t)b * C * HW;

  for (int tile = 0; tile < 4; ++tile) {
    int h  = h0 + (tile >> 1);
    int wb = (tile & 1) << 7;
    __syncthreads();
    #pragma unroll
    for (int cc = 0; cc < 8; ++cc) {
      int c = cg + (cc << 3);
      lds4[c * 33 + p4l] =
          *((const f32x4*)(x + bbase + (size_t)c * HW + h * W + wb) + p4l);
    }
    __syncthreads();
    u64* pdst = packed + ((size_t)(b * H + h)) * W + wb;
    #pragma unroll
    for (int k = 0; k < 8; ++k) {
      int p4i = (wid << 3) + k;
      f32x4 v = lds4[lane * 33 + p4i];
      u64 q0 = __ballot(v.x + bm > 0.f);
      u64 q1 = __ballot(v.y + bm > 0.f);
      u64 q2 = __ballot(v.z + bm > 0.f);
      u64 q3 = __ballot(v.w + bm > 0.f);
      u64 qa = (lane & 1) ? q1 : q0;
      u64 qb = (lane & 1) ? q3 : q2;
      u64 qq = (lane & 2) ? qb : qa;
      if (lane < 4) pdst[(p4i << 2) + lane] = qq;
    }
  }
}

// ---------------- K2: gate (R10 identical) ----------------------------------
__global__ __launch_bounds__(512) void k_gate(const float* __restrict__ sums,
                                              const float* __restrict__ w_conv,
                                              const float* __restrict__ w1d,
                                              float* __restrict__ alpha,
                                              u64* __restrict__ wsign) {
  __shared__ float stA[512], stM[512], stS[512];  // [b*64 + c]
  __shared__ float swv[64];
  int tid = threadIdx.x;
  {
    float s = sums[tid], s2 = sums[512 + tid], sa = sums[1024 + tid];
    const float invN = 1.f / (float)HW;
    float mean = s * invN;
    float var  = (s2 - s * s * invN) * (1.f / (float)(HW - 1)) + EPSV;
    stA[tid] = sa * invN;
    stM[tid] = mean;
    stS[tid] = sqrtf(var);
  }
  {
    int o = tid >> 3, g = tid & 7;                 // 8 lanes per out-channel
    const float* wo = w_conv + o * 576 + g * 72;   // 8 in-channels x 9 taps
    float s = 0.f;
    u64 wb[9] = {0,0,0,0,0,0,0,0,0};
    #pragma unroll
    for (int i = 0; i < 8; i++) {
      #pragma unroll
      for (int tp = 0; tp < 9; tp++) {
        float v = wo[i * 9 + tp];
        s += fabsf(v);
        if (v > 0.f) wb[tp] |= (1ull << (g * 8 + i));
      }
    }
    #pragma unroll
    for (int off = 4; off > 0; off >>= 1) {
      s += __shfl_down(s, off, 8);
      #pragma unroll
      for (int tp = 0; tp < 9; tp++)
        wb[tp] |= __shfl_down(wb[tp], off, 8);
    }
    if (g == 0) {
      swv[o] = s * (1.f / 576.f);
      #pragma unroll
      for (int tp = 0; tp < 9; tp++) wsign[o * 9 + tp] = wb[tp];
    }
  }
  __syncthreads();
  int b = tid >> 6, c = tid & 63;
  float y = 0.f;
  #pragma unroll
  for (int k = 0; k < 3; k++) {
    int cc = c + k - 1;
    if (cc >= 0 && cc < 64) {
      int j = b * 64 + cc;
      y += stA[j] * w1d[0 * 3 + k] + stM[j] * w1d[1 * 3 + k] + stS[j] * w1d[2 * 3 + k];
    }
  }
  float gate = 1.f / (1.f + expf(-y));
  alpha[tid] = gate * swv[c];   // folds scale_w[o] * gate[b][o]
}

// ------- K3: XNOR conv, 4 px/thread; neighborhood PINNED in registers -------
// 2048 blocks: blk = b*256 + hg*4 + oq. Block: 4-row strip, o in [oq*16, +16).
__global__ __launch_bounds__(256, 4) void k_conv4(const u64* __restrict__ packed,
                                                  const u64* __restrict__ wsign,
                                                  const float* __restrict__ alpha,
                                                  const float* __restrict__ x,
                                                  const float* __restrict__ pr_b0,
                                                  const float* __restrict__ prelu_a,
                                                  const float* __restrict__ pr_b1,
                                                  float* __restrict__ out) {
  int blk = blockIdx.x;
  int oq = blk & 3;
  int hg = (blk >> 2) & 63;
  int b  = blk >> 8;
  int h0 = hg << 2;
  int t = threadIdx.x;
  __shared__ u64 rows[6][W];          // packed rows h0-1 .. h0+4
  const u64* pb = packed + (size_t)b * H * W;
  #pragma unroll
  for (int r = 0; r < 6; ++r) {
    int hr = h0 - 1 + r;
    rows[r][t] = (hr >= 0 && hr < H) ? pb[hr * W + t] : 0ull;
  }
  __syncthreads();

  int tr = t >> 6, lane = t & 63;
  int tw = lane << 2;
  int h  = h0 + tr;
  bool rTop = (h > 0), rBot = (h < H - 1);       // wave-uniform
  u64 vm0 = (lane == 0)  ? 0ull : ~0ull;
  u64 vm5 = (lane == 63) ? 0ull : ~0ull;

  int iL = (tw > 0) ? tw - 1 : 0;
  int iR = (tw + 4 < W) ? tw + 4 : W - 1;
  const u64* rT = rows[tr];
  const u64* rM = rows[tr + 1];
  const u64* rB = rows[tr + 2];

  // Named neighborhood registers, pinned so the compiler cannot rematerialize
  // them from LDS inside the o-loop (R9: VGPR_Count=32 proved it did).
  u64 a0 = rT[iL], a1 = rT[tw], a2 = rT[tw+1], a3 = rT[tw+2], a4 = rT[tw+3], a5 = rT[iR];
  u64 m0 = rM[iL], m1 = rM[tw], m2 = rM[tw+1], m3 = rM[tw+2], m4 = rM[tw+3], m5 = rM[iR];
  u64 b0_ = rB[iL], b1_ = rB[tw], b2_ = rB[tw+1], b3_ = rB[tw+2], b4_ = rB[tw+3], b5_ = rB[iR];
  asm volatile("" : "+v"(a0), "+v"(a1), "+v"(a2), "+v"(a3), "+v"(a4), "+v"(a5));
  asm volatile("" : "+v"(m0), "+v"(m1), "+v"(m2), "+v"(m3), "+v"(m4), "+v"(m5));
  asm volatile("" : "+v"(b0_), "+v"(b1_), "+v"(b2_), "+v"(b3_), "+v"(b4_), "+v"(b5_));

  int nr = 1 + (int)rTop + (int)rBot;
  float base0 = 64.f * (float)nr * ((lane == 0)  ? 2.f : 3.f);
  float base1 = 64.f * (float)nr * 3.f;
  float base3 = 64.f * (float)nr * ((lane == 63) ? 2.f : 3.f);

  int o0 = oq << 4;
  size_t xoff = (size_t)b * C * HW + (size_t)(o0) * HW + (size_t)h * W + tw;
  const float* al = alpha + b * 64 + o0;
  const float* pb0 = pr_b0 + o0;
  const float* ppa = prelu_a + o0;
  const float* pb1 = pr_b1 + o0;
  const u64* wsq = wsign + (size_t)o0 * 9;

  for (int oo = 0; oo < 16; ++oo) {
    const u64* ws = wsq + oo * 9;
    u64 w0=ws[0], w1=ws[1], w2=ws[2], w3=ws[3], w4=ws[4],
        w5=ws[5], w6=ws[6], w7=ws[7], w8=ws[8];
    f32x4 xr = *(const f32x4*)(x + xoff + (size_t)oo * HW);
    int c0 = 0, c1 = 0, c2 = 0, c3 = 0;
    if (rTop) {
      c0 += __popcll((a0^w0)&vm0) + __popcll(a1^w1) + __popcll(a2^w2);
      c1 += __popcll(a1^w0) + __popcll(a2^w1) + __popcll(a3^w2);
      c2 += __popcll(a2^w0) + __popcll(a3^w1) + __popcll(a4^w2);
      c3 += __popcll(a3^w0) + __popcll(a4^w1) + __popcll((a5^w2)&vm5);
    }
    {
      c0 += __popcll((m0^w3)&vm0) + __popcll(m1^w4) + __popcll(m2^w5);
      c1 += __popcll(m1^w3) + __popcll(m2^w4) + __popcll(m3^w5);
      c2 += __popcll(m2^w3) + __popcll(m3^w4) + __popcll(m4^w5);
      c3 += __popcll(m3^w3) + __popcll(m4^w4) + __popcll((m5^w5)&vm5);
    }
    if (rBot) {
      c0 += __popcll((b0_^w6)&vm0) + __popcll(b1_^w7) + __popcll(b2_^w8);
      c1 += __popcll(b1_^w6) + __popcll(b2_^w7) + __popcll(b3_^w8);
      c2 += __popcll(b2_^w6) + __popcll(b3_^w7) + __popcll(b4_^w8);
      c3 += __popcll(b3_^w6) + __popcll(b4_^w7) + __popcll((b5_^w8)&vm5);
    }
    float a  = al[oo];
    float bb0 = pb0[oo], pa = ppa[oo], bb1 = pb1[oo];
    float d0 = (base0 - 2.f*(float)c0) * a + bb0;
    float d1 = (base1 - 2.f*(float)c1) * a + bb0;
    float d2 = (base1 - 2.f*(float)c2) * a + bb0;
    float d3 = (base3 - 2.f*(float)c3) * a + bb0;
    d0 = (d0 > 0.f) ? d0 : pa * d0;
    d1 = (d1 > 0.f) ? d1 : pa * d1;
    d2 = (d2 > 0.f) ? d2 : pa * d2;
    d3 = (d3 > 0.f) ? d3 : pa * d3;
    f32x4 ov;
    ov.x = d0 + bb1 + xr.x;
    ov.y = d1 + bb1 + xr.y;
    ov.z = d2 + bb1 + xr.z;
    ov.w = d3 + bb1 + xr.w;
    __builtin_nontemporal_store(ov, (f32x4*)(out + xoff + (size_t)oo * HW));
  }
}

extern "C" void kernel_launch(void* const* d_in, const int* in_sizes, int n_in,
                              void* d_out, int out_size, void* d_ws, size_t ws_size,
                              hipStream_t stream) {
  const float* x       = (const float*)d_in[0];
  const float* b_move  = (const float*)d_in[1];
  const float* w_conv  = (const float*)d_in[2];
  const float* w1d     = (const float*)d_in[3];
  const float* pr_b0   = (const float*)d_in[4];
  const float* prelu_a = (const float*)d_in[5];
  const float* pr_b1   = (const float*)d_in[6];
  float* out = (float*)d_out;

  char* ws = (char*)d_ws;
  // ws: packed u64[8*256*256] = 4 MiB; sums 3*512 f32; alpha 512 f32; wsign 576 u64
  u64*   packed = (u64*)ws;
  float* sums   = (float*)(ws + 4194304);
  float* alpha  = (float*)(ws + 4194304 + 8192);
  u64*   wsign  = (u64*)(ws + 4194304 + 16384);

  k_stats<<<512, 256, 0, stream>>>(x, b_move, sums);
  k_pack<<<1024, 256, 0, stream>>>(x, b_move, packed);
  k_gate<<<1, 512, 0, stream>>>(sums, w_conv, w1d, alpha, wsign);
  k_conv4<<<2048, 256, 0, stream>>>(packed, wsign, alpha, x,
                                    pr_b0, prelu_a, pr_b1, out);
}

// Round 13
// 105.557 us; speedup vs baseline: 1.3606x; 1.0137x over previous
//
#include <hip/hip_runtime.h>
#include <stdint.h>

#define BB 8
#define C  64
#define H  256
#define W  256
#define HW (H*W)
#define EPSV 1e-6f

typedef unsigned long long u64;
typedef float __attribute__((ext_vector_type(4))) f32x4;

// ------- K1: merged stats ∥ pack via block-role split (grid = 1536) ---------
// id%3==0 -> stats block (bc = id/3, 512 of them): streaming per-(b,c) stats.
// else    -> pack block (pidx = id - id/3 - 1, 1024 of them): R6 LDS-transpose
//            + ballot sign-pack. Roles interleave across CUs: stats' HBM-bound
//            phase overlaps pack's LDS/VALU-bound phase.
__global__ __launch_bounds__(256) void k_sp(const float* __restrict__ x,
                                            const float* __restrict__ bmove,
                                            float* __restrict__ sums /* [3][512] */,
                                            u64* __restrict__ packed) {
  __shared__ f32x4 lds4[64 * 33];
  __shared__ float red[4][3];
  int id = blockIdx.x;
  int q3 = id / 3;
  if (id - q3 * 3 == 0) {
    // ---------------- stats role (R6 k_stats body) ----------------
    int bc = q3;
    float bm = bmove[bc & 63];
    const f32x4* p = (const f32x4*)(x + (size_t)bc * HW);
    int t = threadIdx.x;
    float s = 0.f, s2 = 0.f, sa = 0.f;
    #pragma unroll 8
    for (int k = 0; k < 64; ++k) {
      f32x4 v = p[(k << 8) | t];
      float a0 = v.x + bm, a1 = v.y + bm, a2 = v.z + bm, a3 = v.w + bm;
      s  += a0 + a1 + a2 + a3;
      s2 += a0*a0 + a1*a1 + a2*a2 + a3*a3;
      sa += fabsf(a0) + fabsf(a1) + fabsf(a2) + fabsf(a3);
    }
    #pragma unroll
    for (int off = 32; off > 0; off >>= 1) {
      s  += __shfl_down(s,  off, 64);
      s2 += __shfl_down(s2, off, 64);
      sa += __shfl_down(sa, off, 64);
    }
    int wid = t >> 6;
    if ((t & 63) == 0) { red[wid][0] = s; red[wid][1] = s2; red[wid][2] = sa; }
    __syncthreads();
    if (t == 0) {
      float S  = red[0][0] + red[1][0] + red[2][0] + red[3][0];
      float S2 = red[0][1] + red[1][1] + red[2][1] + red[3][1];
      float SA = red[0][2] + red[1][2] + red[2][2] + red[3][2];
      sums[bc] = S; sums[512 + bc] = S2; sums[1024 + bc] = SA;
    }
  } else {
    // ---------------- pack role (R6 k_pack body) ----------------
    int blk = id - q3 - 1;
    int b   = blk >> 7;
    int rg  = blk & 127;
    int h0  = rg << 1;
    int tid = threadIdx.x;
    int wid = tid >> 6, lane = tid & 63;

    float bm = bmove[lane];               // lane = channel in consume phase
    int p4l = tid & 31;
    int cg  = tid >> 5;
    const size_t bbase = (size_t)b * C * HW;

    for (int tile = 0; tile < 4; ++tile) {
      int h  = h0 + (tile >> 1);
      int wb = (tile & 1) << 7;
      __syncthreads();
      #pragma unroll
      for (int cc = 0; cc < 8; ++cc) {
        int c = cg + (cc << 3);
        lds4[c * 33 + p4l] =
            *((const f32x4*)(x + bbase + (size_t)c * HW + h * W + wb) + p4l);
      }
      __syncthreads();
      u64* pdst = packed + ((size_t)(b * H + h)) * W + wb;
      #pragma unroll
      for (int k = 0; k < 8; ++k) {
        int p4i = (wid << 3) + k;
        f32x4 v = lds4[lane * 33 + p4i];
        u64 q0 = __ballot(v.x + bm > 0.f);
        u64 q1 = __ballot(v.y + bm > 0.f);
        u64 q2 = __ballot(v.z + bm > 0.f);
        u64 q3b = __ballot(v.w + bm > 0.f);
        u64 qa = (lane & 1) ? q1 : q0;
        u64 qb = (lane & 1) ? q3b : q2;
        u64 qq = (lane & 2) ? qb : qa;
        if (lane < 4) pdst[(p4i << 2) + lane] = qq;
      }
    }
  }
}

// ---------------- K2: gate (R6 identical) -----------------------------------
__global__ __launch_bounds__(512) void k_gate(const float* __restrict__ sums,
                                              const float* __restrict__ w_conv,
                                              const float* __restrict__ w1d,
                                              float* __restrict__ alpha,
                                              u64* __restrict__ wsign) {
  __shared__ float stA[512], stM[512], stS[512];  // [b*64 + c]
  __shared__ float swv[64];
  int tid = threadIdx.x;
  {
    float s = sums[tid], s2 = sums[512 + tid], sa = sums[1024 + tid];
    const float invN = 1.f / (float)HW;
    float mean = s * invN;
    float var  = (s2 - s * s * invN) * (1.f / (float)(HW - 1)) + EPSV;
    stA[tid] = sa * invN;
    stM[tid] = mean;
    stS[tid] = sqrtf(var);
  }
  {
    int o = tid >> 3, g = tid & 7;                 // 8 lanes per out-channel
    const float* wo = w_conv + o * 576 + g * 72;   // 8 in-channels x 9 taps
    float s = 0.f;
    u64 wb[9] = {0,0,0,0,0,0,0,0,0};
    #pragma unroll
    for (int i = 0; i < 8; i++) {
      #pragma unroll
      for (int tp = 0; tp < 9; tp++) {
        float v = wo[i * 9 + tp];
        s += fabsf(v);
        if (v > 0.f) wb[tp] |= (1ull << (g * 8 + i));
      }
    }
    #pragma unroll
    for (int off = 4; off > 0; off >>= 1) {
      s += __shfl_down(s, off, 8);
      #pragma unroll
      for (int tp = 0; tp < 9; tp++)
        wb[tp] |= __shfl_down(wb[tp], off, 8);
    }
    if (g == 0) {
      swv[o] = s * (1.f / 576.f);
      #pragma unroll
      for (int tp = 0; tp < 9; tp++) wsign[o * 9 + tp] = wb[tp];
    }
  }
  __syncthreads();
  int b = tid >> 6, c = tid & 63;
  float y = 0.f;
  #pragma unroll
  for (int k = 0; k < 3; k++) {
    int cc = c + k - 1;
    if (cc >= 0 && cc < 64) {
      int j = b * 64 + cc;
      y += stA[j] * w1d[0 * 3 + k] + stM[j] * w1d[1 * 3 + k] + stS[j] * w1d[2 * 3 + k];
    }
  }
  float gate = 1.f / (1.f + expf(-y));
  alpha[tid] = gate * swv[c];   // folds scale_w[o] * gate[b][o]
}

// ---------------- K3: XNOR conv, 4 px/thread, o-split x4 (R6 identical) -----
// 2048 blocks: blk = b*256 + hg*4 + oq. Block: 4-row strip, o in [oq*16, +16).
__global__ __launch_bounds__(256) void k_conv4(const u64* __restrict__ packed,
                                               const u64* __restrict__ wsign,
                                               const float* __restrict__ alpha,
                                               const float* __restrict__ x,
                                               const float* __restrict__ pr_b0,
                                               const float* __restrict__ prelu_a,
                                               const float* __restrict__ pr_b1,
                                               float* __restrict__ out) {
  int blk = blockIdx.x;
  int oq = blk & 3;
  int hg = (blk >> 2) & 63;
  int b  = blk >> 8;
  int h0 = hg << 2;
  int t = threadIdx.x;
  __shared__ u64 rows[6][W];          // packed rows h0-1 .. h0+4
  const u64* pb = packed + (size_t)b * H * W;
  #pragma unroll
  for (int r = 0; r < 6; ++r) {
    int hr = h0 - 1 + r;
    rows[r][t] = (hr >= 0 && hr < H) ? pb[hr * W + t] : 0ull;
  }
  __syncthreads();

  int tr = t >> 6, lane = t & 63;
  int tw = lane << 2;
  int h  = h0 + tr;
  bool rTop = (h > 0), rBot = (h < H - 1);       // wave-uniform
  u64 vm0 = (lane == 0)  ? 0ull : ~0ull;
  u64 vm5 = (lane == 63) ? 0ull : ~0ull;

  u64 nw[3][6];
  #pragma unroll
  for (int rr = 0; rr < 3; ++rr) {
    #pragma unroll
    for (int j = 0; j < 6; ++j) {
      int wi = tw - 1 + j;
      wi = (wi < 0) ? 0 : (wi > W - 1 ? W - 1 : wi);
      nw[rr][j] = rows[tr + rr][wi];
    }
  }
  int nr = 1 + (int)rTop + (int)rBot;
  float base0 = 64.f * (float)nr * ((lane == 0)  ? 2.f : 3.f);
  float base1 = 64.f * (float)nr * 3.f;
  float base3 = 64.f * (float)nr * ((lane == 63) ? 2.f : 3.f);

  int o0 = oq << 4;
  size_t xoff = (size_t)b * C * HW + (size_t)(o0) * HW + (size_t)h * W + tw;
  const float* al = alpha + b * 64 + o0;
  const float* pb0 = pr_b0 + o0;
  const float* ppa = prelu_a + o0;
  const float* pb1 = pr_b1 + o0;
  const u64* wsq = wsign + (size_t)o0 * 9;

  #pragma unroll 2
  for (int oo = 0; oo < 16; ++oo) {
    const u64* ws = wsq + oo * 9;
    u64 w0=ws[0], w1=ws[1], w2=ws[2], w3=ws[3], w4=ws[4],
        w5=ws[5], w6=ws[6], w7=ws[7], w8=ws[8];
    f32x4 xr = *(const f32x4*)(x + xoff + (size_t)oo * HW);
    int c0 = 0, c1 = 0, c2 = 0, c3 = 0;
    if (rTop) {
      c0 += __popcll((nw[0][0]^w0)&vm0) + __popcll(nw[0][1]^w1) + __popcll(nw[0][2]^w2);
      c1 += __popcll(nw[0][1]^w0) + __popcll(nw[0][2]^w1) + __popcll(nw[0][3]^w2);
      c2 += __popcll(nw[0][2]^w0) + __popcll(nw[0][3]^w1) + __popcll(nw[0][4]^w2);
      c3 += __popcll(nw[0][3]^w0) + __popcll(nw[0][4]^w1) + __popcll((nw[0][5]^w2)&vm5);
    }
    {
      c0 += __popcll((nw[1][0]^w3)&vm0) + __popcll(nw[1][1]^w4) + __popcll(nw[1][2]^w5);
      c1 += __popcll(nw[1][1]^w3) + __popcll(nw[1][2]^w4) + __popcll(nw[1][3]^w5);
      c2 += __popcll(nw[1][2]^w3) + __popcll(nw[1][3]^w4) + __popcll(nw[1][4]^w5);
      c3 += __popcll(nw[1][3]^w3) + __popcll(nw[1][4]^w4) + __popcll((nw[1][5]^w5)&vm5);
    }
    if (rBot) {
      c0 += __popcll((nw[2][0]^w6)&vm0) + __popcll(nw[2][1]^w7) + __popcll(nw[2][2]^w8);
      c1 += __popcll(nw[2][1]^w6) + __popcll(nw[2][2]^w7) + __popcll(nw[2][3]^w8);
      c2 += __popcll(nw[2][2]^w6) + __popcll(nw[2][3]^w7) + __popcll(nw[2][4]^w8);
      c3 += __popcll(nw[2][3]^w6) + __popcll(nw[2][4]^w7) + __popcll((nw[2][5]^w8)&vm5);
    }
    float a  = al[oo];
    float b0 = pb0[oo], pa = ppa[oo], b1 = pb1[oo];
    float d0 = (base0 - 2.f*(float)c0) * a + b0;
    float d1 = (base1 - 2.f*(float)c1) * a + b0;
    float d2 = (base1 - 2.f*(float)c2) * a + b0;
    float d3 = (base3 - 2.f*(float)c3) * a + b0;
    d0 = (d0 > 0.f) ? d0 : pa * d0;
    d1 = (d1 > 0.f) ? d1 : pa * d1;
    d2 = (d2 > 0.f) ? d2 : pa * d2;
    d3 = (d3 > 0.f) ? d3 : pa * d3;
    f32x4 ov;
    ov.x = d0 + b1 + xr.x;
    ov.y = d1 + b1 + xr.y;
    ov.z = d2 + b1 + xr.z;
    ov.w = d3 + b1 + xr.w;
    __builtin_nontemporal_store(ov, (f32x4*)(out + xoff + (size_t)oo * HW));
  }
}

extern "C" void kernel_launch(void* const* d_in, const int* in_sizes, int n_in,
                              void* d_out, int out_size, void* d_ws, size_t ws_size,
                              hipStream_t stream) {
  const float* x       = (const float*)d_in[0];
  const float* b_move  = (const float*)d_in[1];
  const float* w_conv  = (const float*)d_in[2];
  const float* w1d     = (const float*)d_in[3];
  const float* pr_b0   = (const float*)d_in[4];
  const float* prelu_a = (const float*)d_in[5];
  const float* pr_b1   = (const float*)d_in[6];
  float* out = (float*)d_out;

  char* ws = (char*)d_ws;
  // ws: packed u64[8*256*256] = 4 MiB; sums 3*512 f32; alpha 512 f32; wsign 576 u64
  u64*   packed = (u64*)ws;
  float* sums   = (float*)(ws + 4194304);
  float* alpha  = (float*)(ws + 4194304 + 8192);
  u64*   wsign  = (u64*)(ws + 4194304 + 16384);

  k_sp<<<1536, 256, 0, stream>>>(x, b_move, sums, packed);
  k_gate<<<1, 512, 0, stream>>>(sums, w_conv, w1d, alpha, wsign);
  k_conv4<<<2048, 256, 0, stream>>>(packed, wsign, alpha, x,
                                    pr_b0, prelu_a, pr_b1, out);
}